// Round 5
// baseline (164.118 us; speedup 1.0000x reference)
//
#include <hip/hip_runtime.h>
#include <hip/hip_bf16.h>
#include <math.h>

// B=8, T=1024, C=768, H=12, D=64
#define Bq 8
#define Tq 1024
#define Cq 768
#define Hq 12
#define Dq 64
#define MROWS (Bq*Tq)      // 8192
#define N_QKV (3*Cq)       // 2304

typedef __bf16 bf16;
typedef bf16 bf16x8 __attribute__((ext_vector_type(8)));
typedef float f32x4 __attribute__((ext_vector_type(4)));

#define MFMA16x16x32(a, b, c) __builtin_amdgcn_mfma_f32_16x16x32_bf16((a), (b), (c), 0, 0, 0)

// All LDS tiles have 128-byte rows (64 bf16). XOR-swizzle 16B chunks within a
// row by the row's low 3 bits (T2) -> stride-128B column reads conflict-free.
__device__ __forceinline__ bf16x8& lds_v8(bf16* base, int row, int byteoff) {
    return *reinterpret_cast<bf16x8*>(
        reinterpret_cast<char*>(base) + row * 128 + (byteoff ^ ((row & 7) << 4)));
}
__device__ __forceinline__ bf16& lds_s16(bf16* base, int row, int byteoff) {
    return *reinterpret_cast<bf16*>(
        reinterpret_cast<char*>(base) + row * 128 + (byteoff ^ ((row & 7) << 4)));
}

// async global->LDS DMA, 16B per lane; LDS dest is wave-uniform base + lane*16.
// Content swizzle via pre-swizzled per-lane GLOBAL source (rule #21).
typedef __attribute__((address_space(3))) unsigned int lds_u32;
typedef const __attribute__((address_space(1))) unsigned int glb_u32;
__device__ __forceinline__ void gload16(const void* g, void* lds) {
    __builtin_amdgcn_global_load_lds((glb_u32*)(uintptr_t)g,
                                     (lds_u32*)(unsigned int)(uintptr_t)lds,
                                     16, 0, 0);
}

// ---------------- helpers: f32 -> bf16 convert / transpose -------------------
__global__ __launch_bounds__(256) void f32_to_bf16(const float* __restrict__ in,
                                                   bf16* __restrict__ out, int n8) {
    int i = blockIdx.x * 256 + threadIdx.x;
    if (i >= n8) return;
    const float4* p = reinterpret_cast<const float4*>(in) + (size_t)i * 2;
    float4 a = p[0], b = p[1];
    bf16x8 o;
    o[0] = (bf16)a.x; o[1] = (bf16)a.y; o[2] = (bf16)a.z; o[3] = (bf16)a.w;
    o[4] = (bf16)b.x; o[5] = (bf16)b.y; o[6] = (bf16)b.z; o[7] = (bf16)b.w;
    reinterpret_cast<bf16x8*>(out)[i] = o;
}

// in[R][C] (f32) -> out[C][R] (bf16)
__global__ __launch_bounds__(256) void transpose_f32_bf16(const float* __restrict__ in,
                                                          bf16* __restrict__ out,
                                                          int R, int C) {
    int idx = blockIdx.x * 256 + threadIdx.x;
    if (idx >= R * C) return;
    int c = idx / R;
    int r = idx - c * R;
    out[idx] = (bf16)in[(size_t)r * C + c];
}

// ---------------- QKV GEMM (bf16 MFMA, dbuf DMA): [8192x768]x[768x2304] ------
__global__ __launch_bounds__(256) void gemm_qkv(const bf16* __restrict__ A,
                                                const bf16* __restrict__ Bt,
                                                const float* __restrict__ bias,
                                                bf16* __restrict__ Qo,
                                                bf16* __restrict__ Ko,
                                                bf16* __restrict__ Vto) {
    __shared__ bf16 As[2][128 * 64];
    __shared__ bf16 Bs[2][128 * 64];
    const int tid = threadIdx.x;
    const int w = tid >> 6, l = tid & 63;
    const int lane16 = l & 15, kg = l >> 4;
    const int wr = w >> 1, wc = w & 1;
    // XCD-aware bijective swizzle: 1152 blocks, each XCD gets 8 bm-rows x 18 bn
    const int flat = blockIdx.y * gridDim.x + blockIdx.x;
    const int nid = (flat & 7) * 144 + (flat >> 3);
    const int bn0 = (nid % 18) * 128, bm0 = (nid / 18) * 128;

    auto stage = [&](int k0, int buf) {
        #pragma unroll
        for (int j = 0; j < 4; ++j) {
            const int q8 = w * 4 + j;          // 1KB block 0..15
            const int r  = q8 * 8 + (l >> 3);  // tile row 0..127
            const int c16 = (l & 7) ^ (r & 7); // pre-swizzled source chunk
            gload16(A + (size_t)(bm0 + r) * Cq + k0 + c16 * 8, &As[buf][q8 * 512]);
            gload16(Bt + (size_t)(bn0 + r) * Cq + k0 + c16 * 8, &Bs[buf][q8 * 512]);
        }
    };

    f32x4 acc[4][4] = {};
    stage(0, 0);
    __syncthreads();
    for (int kt = 0; kt < 12; ++kt) {
        if (kt < 11) stage((kt + 1) * 64, (kt + 1) & 1);   // DMA overlaps compute
        bf16* Ac = As[kt & 1];
        bf16* Bc = Bs[kt & 1];
        #pragma unroll
        for (int ks = 0; ks < 2; ++ks) {
            bf16x8 af[4], bfr[4];
            #pragma unroll
            for (int m = 0; m < 4; ++m)
                af[m] = lds_v8(Ac, wr * 64 + m * 16 + lane16, ks * 64 + kg * 16);
            #pragma unroll
            for (int n = 0; n < 4; ++n)
                bfr[n] = lds_v8(Bc, wc * 64 + n * 16 + lane16, ks * 64 + kg * 16);
            #pragma unroll
            for (int m = 0; m < 4; ++m)
                #pragma unroll
                for (int n = 0; n < 4; ++n)
                    acc[m][n] = MFMA16x16x32(af[m], bfr[n], acc[m][n]);
        }
        __syncthreads();   // vmcnt drain = next buffer's DMA complete
    }
    const int mrow0 = bm0 + wr * 64;
    const int ncol0 = bn0 + wc * 64;
    #pragma unroll
    for (int mi = 0; mi < 4; ++mi) {
        #pragma unroll
        for (int r = 0; r < 4; ++r) {
            const int grow = mrow0 + mi * 16 + kg * 4 + r;
            const int bb = grow >> 10, tt = grow & 1023;
            #pragma unroll
            for (int ni = 0; ni < 4; ++ni) {
                const int gcol = ncol0 + ni * 16 + lane16;
                const float v = acc[mi][ni][r] + bias[gcol];
                const int which = gcol / Cq;
                const int hn = gcol - which * Cq;
                const int h = hn >> 6, d = hn & 63;
                const size_t bh = (size_t)bb * Hq + h;
                if (which == 0)      Qo[(bh * Tq + tt) * Dq + d] = (bf16)(v * 0.125f);
                else if (which == 1) Ko[(bh * Tq + tt) * Dq + d] = (bf16)v;
                else                 Vto[(bh * Dq + d) * Tq + tt] = (bf16)v;
            }
        }
    }
}

// ---------------- Flash causal attention (bf16 MFMA, 8-wave paired tiles) ----
// 512 thr / 8 waves. Waves 0-3 own q-tile qhi (16 rows each), waves 4-7 own
// qlo -> the two softmax chains run in parallel waves. Shared dbuf K/V (DMA
// per wave halves), per-wave P. Grid 768, XCD head-locality mapping.
__global__ __launch_bounds__(512) void attn_mfma(const bf16* __restrict__ Q,
                                                 const bf16* __restrict__ K,
                                                 const bf16* __restrict__ Vt,
                                                 bf16* __restrict__ Y) {
    __shared__ bf16 Kl[2][64 * 64];
    __shared__ bf16 Vl[2][64 * 64];
    __shared__ bf16 Pl[8 * 16 * 64];
    const int tid = threadIdx.x;
    const int w = tid >> 6, l = tid & 63;
    const int wq = w & 3, side = w >> 2;       // side 0 = qhi, 1 = qlo
    const int lane16 = l & 15, kg = l >> 4;
    const int id = blockIdx.x;                 // 0..767
    const int xcd = id & 7, j = id >> 3;       // j 0..95
    const int bh = xcd * 12 + (j >> 3);        // 12 heads per XCD
    const int qlo = j & 7, qhi = 15 - qlo;
    const int myq = side ? qlo : qhi;
    const size_t hoff = (size_t)bh * Tq * Dq;
    bf16* Pw = Pl + w * 16 * 64;
    const int qloc = wq * 16 + kg * 4;         // local q-row of frag r=0

    const int qrow = myq * 64 + wq * 16;
    const bf16x8 qf0 = *reinterpret_cast<const bf16x8*>(Q + hoff + (size_t)(qrow + lane16) * Dq + kg * 8);
    const bf16x8 qf1 = *reinterpret_cast<const bf16x8*>(Q + hoff + (size_t)(qrow + lane16) * Dq + 32 + kg * 8);

    f32x4 of[4] = {};
    float mr[4], lr[4];
    #pragma unroll
    for (int r = 0; r < 4; ++r) { mr[r] = -INFINITY; lr[r] = 0.f; }

    auto stage = [&](int t, int buf) {
        const int r  = w * 8 + (l >> 3);       // tile row 0..63
        const int c16 = (l & 7) ^ (r & 7);
        gload16(K + hoff + (size_t)(t * 64 + r) * Dq + c16 * 8, &Kl[buf][w * 512]);
        gload16(Vt + hoff + (size_t)r * Tq + t * 64 + c16 * 8, &Vl[buf][w * 512]);
    };

    auto process = [&](bool diag, bf16* Kc, bf16* Vc) {
        f32x4 sf[4];
        #pragma unroll
        for (int f = 0; f < 4; ++f) {
            f32x4 z = {};
            z = MFMA16x16x32(qf0, lds_v8(Kc, f * 16 + lane16, kg * 16), z);
            z = MFMA16x16x32(qf1, lds_v8(Kc, f * 16 + lane16, 64 + kg * 16), z);
            sf[f] = z;
        }
        if (diag) {
            #pragma unroll
            for (int f = 0; f < 4; ++f)
                #pragma unroll
                for (int r = 0; r < 4; ++r)
                    if (f * 16 + lane16 > qloc + r) sf[f][r] = -INFINITY;
        }
        float mt[4];
        #pragma unroll
        for (int r = 0; r < 4; ++r) mt[r] = -INFINITY;
        #pragma unroll
        for (int f = 0; f < 4; ++f)
            #pragma unroll
            for (int r = 0; r < 4; ++r) mt[r] = fmaxf(mt[r], sf[f][r]);
        #pragma unroll
        for (int r = 0; r < 4; ++r) {
            #pragma unroll
            for (int m = 1; m < 16; m <<= 1) mt[r] = fmaxf(mt[r], __shfl_xor(mt[r], m));
            const float mn = fmaxf(mr[r], mt[r]);
            const float a = __expf(mr[r] - mn);
            mr[r] = mn;
            lr[r] *= a;
            #pragma unroll
            for (int dg = 0; dg < 4; ++dg) of[dg][r] *= a;
        }
        float lt[4] = {0.f, 0.f, 0.f, 0.f};
        #pragma unroll
        for (int f = 0; f < 4; ++f)
            #pragma unroll
            for (int r = 0; r < 4; ++r) {
                const float p = __expf(sf[f][r] - mr[r]);
                lt[r] += p;
                lds_s16(Pw, kg * 4 + r, (f * 16 + lane16) * 2) = (bf16)p;
            }
        #pragma unroll
        for (int r = 0; r < 4; ++r) {
            #pragma unroll
            for (int m = 1; m < 16; m <<= 1) lt[r] += __shfl_xor(lt[r], m);
            lr[r] += lt[r];
        }
        #pragma unroll
        for (int ks = 0; ks < 2; ++ks) {
            bf16x8 pf = lds_v8(Pw, lane16, ks * 64 + kg * 16);
            #pragma unroll
            for (int dg = 0; dg < 4; ++dg) {
                bf16x8 vf = lds_v8(Vc, dg * 16 + lane16, ks * 64 + kg * 16);
                of[dg] = MFMA16x16x32(pf, vf, of[dg]);
            }
        }
    };

    stage(0, 0);
    __syncthreads();

    for (int t = 0; t <= qhi; ++t) {
        if (t < qhi) stage(t + 1, (t + 1) & 1);     // DMA overlaps compute
        bf16* Kc = Kl[t & 1];
        bf16* Vc = Vl[t & 1];
        if (side == 0 || t <= qlo) process(t == myq, Kc, Vc);
        __syncthreads();                            // vmcnt drain = DMA complete
    }

    const int b = bh / Hq, h = bh - b * Hq;
    #pragma unroll
    for (int r = 0; r < 4; ++r) {
        const float inv = 1.f / lr[r];
        bf16* yp = Y + (size_t)(b * Tq + qrow + kg * 4 + r) * Cq + h * Dq;
        #pragma unroll
        for (int dg = 0; dg < 4; ++dg)
            yp[dg * 16 + lane16] = (bf16)(of[dg][r] * inv);
    }
}

// ---------------- Proj GEMM (bf16 MFMA, dbuf DMA): [8192x768]x[768x768] ------
__global__ __launch_bounds__(256) void gemm_proj(const bf16* __restrict__ A,
                                                 const bf16* __restrict__ Bt,
                                                 const float* __restrict__ bias,
                                                 float* __restrict__ out) {
    __shared__ bf16 As[2][128 * 64];
    __shared__ bf16 Bs[2][128 * 64];
    const int tid = threadIdx.x;
    const int w = tid >> 6, l = tid & 63;
    const int lane16 = l & 15, kg = l >> 4;
    const int wr = w >> 1, wc = w & 1;
    // 384 blocks: each XCD gets 8 bm-rows x 6 bn
    const int flat = blockIdx.y * gridDim.x + blockIdx.x;
    const int nid = (flat & 7) * 48 + (flat >> 3);
    const int bn0 = (nid % 6) * 128, bm0 = (nid / 6) * 128;

    auto stage = [&](int k0, int buf) {
        #pragma unroll
        for (int j = 0; j < 4; ++j) {
            const int q8 = w * 4 + j;
            const int r  = q8 * 8 + (l >> 3);
            const int c16 = (l & 7) ^ (r & 7);
            gload16(A + (size_t)(bm0 + r) * Cq + k0 + c16 * 8, &As[buf][q8 * 512]);
            gload16(Bt + (size_t)(bn0 + r) * Cq + k0 + c16 * 8, &Bs[buf][q8 * 512]);
        }
    };

    f32x4 acc[4][4] = {};
    stage(0, 0);
    __syncthreads();
    for (int kt = 0; kt < 12; ++kt) {
        if (kt < 11) stage((kt + 1) * 64, (kt + 1) & 1);
        bf16* Ac = As[kt & 1];
        bf16* Bc = Bs[kt & 1];
        #pragma unroll
        for (int ks = 0; ks < 2; ++ks) {
            bf16x8 af[4], bfr[4];
            #pragma unroll
            for (int m = 0; m < 4; ++m)
                af[m] = lds_v8(Ac, wr * 64 + m * 16 + lane16, ks * 64 + kg * 16);
            #pragma unroll
            for (int n = 0; n < 4; ++n)
                bfr[n] = lds_v8(Bc, wc * 64 + n * 16 + lane16, ks * 64 + kg * 16);
            #pragma unroll
            for (int m = 0; m < 4; ++m)
                #pragma unroll
                for (int n = 0; n < 4; ++n)
                    acc[m][n] = MFMA16x16x32(af[m], bfr[n], acc[m][n]);
        }
        __syncthreads();
    }
    const int mrow0 = bm0 + wr * 64;
    const int ncol0 = bn0 + wc * 64;
    #pragma unroll
    for (int mi = 0; mi < 4; ++mi) {
        #pragma unroll
        for (int r = 0; r < 4; ++r) {
            const int grow = mrow0 + mi * 16 + kg * 4 + r;
            #pragma unroll
            for (int ni = 0; ni < 4; ++ni) {
                const int gcol = ncol0 + ni * 16 + lane16;
                out[(size_t)grow * Cq + gcol] = acc[mi][ni][r] + bias[gcol];
            }
        }
    }
}

extern "C" void kernel_launch(void* const* d_in, const int* in_sizes, int n_in,
                              void* d_out, int out_size, void* d_ws, size_t ws_size,
                              hipStream_t stream) {
    const float* x      = (const float*)d_in[0];
    const float* w_attn = (const float*)d_in[1];
    const float* b_attn = (const float*)d_in[2];
    const float* w_proj = (const float*)d_in[3];
    const float* b_proj = (const float*)d_in[4];
    float* out = (float*)d_out;

    char* ws = (char*)d_ws;
    bf16* Ax  = (bf16*)ws; ws += (size_t)MROWS * Cq * 2;
    bf16* WaT = (bf16*)ws; ws += (size_t)N_QKV * Cq * 2;
    bf16* WpT = (bf16*)ws; ws += (size_t)Cq * Cq * 2;
    bf16* Qw  = (bf16*)ws; ws += (size_t)MROWS * Cq * 2;   // [B,H,T,D], x0.125
    bf16* Kw  = (bf16*)ws; ws += (size_t)MROWS * Cq * 2;   // [B,H,T,D]
    bf16* Vtw = (bf16*)ws; ws += (size_t)MROWS * Cq * 2;   // [B,H,D,T]
    bf16* Yw  = (bf16*)ws; ws += (size_t)MROWS * Cq * 2;   // attn out [M][C]

    f32_to_bf16<<<(MROWS * Cq / 8 + 255) / 256, 256, 0, stream>>>(x, Ax, MROWS * Cq / 8);
    transpose_f32_bf16<<<(Cq * N_QKV + 255) / 256, 256, 0, stream>>>(w_attn, WaT, Cq, N_QKV);
    transpose_f32_bf16<<<(Cq * Cq + 255) / 256, 256, 0, stream>>>(w_proj, WpT, Cq, Cq);
    gemm_qkv<<<dim3(18, 64), 256, 0, stream>>>(Ax, WaT, b_attn, Qw, Kw, Vtw);
    attn_mfma<<<dim3(768), 512, 0, stream>>>(Qw, Kw, Vtw, Yw);
    gemm_proj<<<dim3(6, 64), 256, 0, stream>>>(Yw, WpT, b_proj, out);
}

// Round 6
// 146.998 us; speedup vs baseline: 1.1165x; 1.1165x over previous
//
#include <hip/hip_runtime.h>
#include <hip/hip_bf16.h>
#include <math.h>

// B=8, T=1024, C=768, H=12, D=64
#define Bq 8
#define Tq 1024
#define Cq 768
#define Hq 12
#define Dq 64
#define MROWS (Bq*Tq)      // 8192
#define N_QKV (3*Cq)       // 2304

typedef __bf16 bf16;
typedef bf16 bf16x8 __attribute__((ext_vector_type(8)));
typedef bf16 bf16x4 __attribute__((ext_vector_type(4)));
typedef float f32x4 __attribute__((ext_vector_type(4)));
typedef float f32x16 __attribute__((ext_vector_type(16)));
typedef unsigned int u32x4 __attribute__((ext_vector_type(4)));

#define MFMA16x16x32(a, b, c) __builtin_amdgcn_mfma_f32_16x16x32_bf16((a), (b), (c), 0, 0, 0)
#define MFMA32x32x16(a, b, c) __builtin_amdgcn_mfma_f32_32x32x16_bf16((a), (b), (c), 0, 0, 0)

// LDS tiles (GEMMs) have 128-byte rows; XOR-swizzle 16B chunks by row low bits.
__device__ __forceinline__ bf16x8& lds_v8(bf16* base, int row, int byteoff) {
    return *reinterpret_cast<bf16x8*>(
        reinterpret_cast<char*>(base) + row * 128 + (byteoff ^ ((row & 7) << 4)));
}

typedef __attribute__((address_space(3))) unsigned int lds_u32;
typedef const __attribute__((address_space(1))) unsigned int glb_u32;
__device__ __forceinline__ void gload16(const void* g, void* lds) {
    __builtin_amdgcn_global_load_lds((glb_u32*)(uintptr_t)g,
                                     (lds_u32*)(unsigned int)(uintptr_t)lds,
                                     16, 0, 0);
}

__device__ __forceinline__ unsigned cvtpk_bf16(float lo, float hi) {
    unsigned r;
    asm volatile("v_cvt_pk_bf16_f32 %0, %1, %2" : "=v"(r) : "v"(lo), "v"(hi));
    return r;
}

// ---------------- helpers: f32 -> bf16 convert / transpose -------------------
__global__ __launch_bounds__(256) void f32_to_bf16(const float* __restrict__ in,
                                                   bf16* __restrict__ out, int n8) {
    int i = blockIdx.x * 256 + threadIdx.x;
    if (i >= n8) return;
    const float4* p = reinterpret_cast<const float4*>(in) + (size_t)i * 2;
    float4 a = p[0], b = p[1];
    bf16x8 o;
    o[0] = (bf16)a.x; o[1] = (bf16)a.y; o[2] = (bf16)a.z; o[3] = (bf16)a.w;
    o[4] = (bf16)b.x; o[5] = (bf16)b.y; o[6] = (bf16)b.z; o[7] = (bf16)b.w;
    reinterpret_cast<bf16x8*>(out)[i] = o;
}

__global__ __launch_bounds__(256) void transpose_f32_bf16(const float* __restrict__ in,
                                                          bf16* __restrict__ out,
                                                          int R, int C) {
    int idx = blockIdx.x * 256 + threadIdx.x;
    if (idx >= R * C) return;
    int c = idx / R;
    int r = idx - c * R;
    out[idx] = (bf16)in[(size_t)r * C + c];
}

// ---------------- QKV GEMM (bf16 MFMA, dbuf DMA): [8192x768]x[768x2304] ------
__global__ __launch_bounds__(256) void gemm_qkv(const bf16* __restrict__ A,
                                                const bf16* __restrict__ Bt,
                                                const float* __restrict__ bias,
                                                bf16* __restrict__ Qo,
                                                bf16* __restrict__ Ko,
                                                bf16* __restrict__ Vto) {
    __shared__ bf16 As[2][128 * 64];
    __shared__ bf16 Bs[2][128 * 64];
    const int tid = threadIdx.x;
    const int w = tid >> 6, l = tid & 63;
    const int lane16 = l & 15, kg = l >> 4;
    const int wr = w >> 1, wc = w & 1;
    const int flat = blockIdx.y * gridDim.x + blockIdx.x;
    const int nid = (flat & 7) * 144 + (flat >> 3);
    const int bn0 = (nid % 18) * 128, bm0 = (nid / 18) * 128;

    auto stage = [&](int k0, int buf) {
        #pragma unroll
        for (int j = 0; j < 4; ++j) {
            const int q8 = w * 4 + j;
            const int r  = q8 * 8 + (l >> 3);
            const int c16 = (l & 7) ^ (r & 7);
            gload16(A + (size_t)(bm0 + r) * Cq + k0 + c16 * 8, &As[buf][q8 * 512]);
            gload16(Bt + (size_t)(bn0 + r) * Cq + k0 + c16 * 8, &Bs[buf][q8 * 512]);
        }
    };

    f32x4 acc[4][4] = {};
    stage(0, 0);
    __syncthreads();
    for (int kt = 0; kt < 12; ++kt) {
        if (kt < 11) stage((kt + 1) * 64, (kt + 1) & 1);
        bf16* Ac = As[kt & 1];
        bf16* Bc = Bs[kt & 1];
        #pragma unroll
        for (int ks = 0; ks < 2; ++ks) {
            bf16x8 af[4], bfr[4];
            #pragma unroll
            for (int m = 0; m < 4; ++m)
                af[m] = lds_v8(Ac, wr * 64 + m * 16 + lane16, ks * 64 + kg * 16);
            #pragma unroll
            for (int n = 0; n < 4; ++n)
                bfr[n] = lds_v8(Bc, wc * 64 + n * 16 + lane16, ks * 64 + kg * 16);
            #pragma unroll
            for (int m = 0; m < 4; ++m)
                #pragma unroll
                for (int n = 0; n < 4; ++n)
                    acc[m][n] = MFMA16x16x32(af[m], bfr[n], acc[m][n]);
        }
        __syncthreads();
    }
    const int mrow0 = bm0 + wr * 64;
    const int ncol0 = bn0 + wc * 64;
    #pragma unroll
    for (int mi = 0; mi < 4; ++mi) {
        #pragma unroll
        for (int r = 0; r < 4; ++r) {
            const int grow = mrow0 + mi * 16 + kg * 4 + r;
            const int bb = grow >> 10, tt = grow & 1023;
            #pragma unroll
            for (int ni = 0; ni < 4; ++ni) {
                const int gcol = ncol0 + ni * 16 + lane16;
                const float v = acc[mi][ni][r] + bias[gcol];
                const int which = gcol / Cq;
                const int hn = gcol - which * Cq;
                const int h = hn >> 6, d = hn & 63;
                const size_t bh = (size_t)bb * Hq + h;
                // Q scale folds 1/sqrt(D) * log2(e) so softmax uses exp2
                if (which == 0)      Qo[(bh * Tq + tt) * Dq + d] = (bf16)(v * 0.18033688011112042f);
                else if (which == 1) Ko[(bh * Tq + tt) * Dq + d] = (bf16)v;
                else                 Vto[(bh * Dq + d) * Tq + tt] = (bf16)v;
            }
        }
    }
}

// ---------------- Flash causal attention (32x32 MFMA, swapped operands) ------
// Warp-autonomous: no LDS, no barriers. Each warp owns 64 q-rows (2x32 subtiles)
// of one head; K/V read from L2/L1. S^T = mfma(K,Q) -> lane owns q-row l&31's
// scores; softmax in-register; PV as O^T = mfma(V^T, P^T) -> rescale lane-local.
__global__ __launch_bounds__(256) void attn_mfma(const bf16* __restrict__ Q,
                                                 const bf16* __restrict__ K,
                                                 const bf16* __restrict__ Vt,
                                                 bf16* __restrict__ Y) {
    const int tid = threadIdx.x;
    const int w = tid >> 6, l = tid & 63;
    const int l31 = l & 31, hi = l >> 5;
    const int b4 = blockIdx.x / 96;            // 0..3, heaviest first
    const int bh = blockIdx.x % 96;            // same head -> same XCD (96%8==0)
    const int qt = 15 - (b4 * 4 + w);          // q64-tile 0..15
    const size_t hoff = (size_t)bh * Tq * Dq;
    const int q0 = qt * 64;

    // Q fragments: qf[sub][ds]: Q[q0+sub*32+l31][ds*16+hi*8 ..+8]
    bf16x8 qf[2][4];
    #pragma unroll
    for (int sub = 0; sub < 2; ++sub)
        #pragma unroll
        for (int ds = 0; ds < 4; ++ds)
            qf[sub][ds] = *reinterpret_cast<const bf16x8*>(
                Q + hoff + (size_t)(q0 + sub * 32 + l31) * Dq + ds * 16 + hi * 8);

    f32x16 o[2][2] = {};                        // [sub][dh]
    float m_[2] = {-INFINITY, -INFINITY};
    float l_[2] = {0.f, 0.f};

    for (int t = 0; t <= qt; ++t) {
        const bf16* Kt  = K  + hoff + (size_t)(t * 64) * Dq;
        const bf16* Vtt = Vt + hoff + t * 64;
        // K frags: kf[kh][ds] = K[t*64+kh*32+l31][ds*16+hi*8..]
        bf16x8 kf[2][4];
        #pragma unroll
        for (int kh = 0; kh < 2; ++kh)
            #pragma unroll
            for (int ds = 0; ds < 4; ++ds)
                kf[kh][ds] = *reinterpret_cast<const bf16x8*>(
                    Kt + (size_t)(kh * 32 + l31) * Dq + ds * 16 + hi * 8);
        // V frags: vf[ks][dh] = Vt[dh*32+l31][t*64+ks*16+hi*8..]
        bf16x8 vf[4][2];
        #pragma unroll
        for (int ks = 0; ks < 4; ++ks)
            #pragma unroll
            for (int dh = 0; dh < 2; ++dh)
                vf[ks][dh] = *reinterpret_cast<const bf16x8*>(
                    Vtt + (size_t)(dh * 32 + l31) * Tq + ks * 16 + hi * 8);

        #pragma unroll
        for (int sub = 0; sub < 2; ++sub) {
            // S^T: lane holds S[k=crow(reg,hi)+kh*32][q=l31]
            f32x16 s[2] = {};
            #pragma unroll
            for (int kh = 0; kh < 2; ++kh)
                #pragma unroll
                for (int ds = 0; ds < 4; ++ds)
                    s[kh] = MFMA32x32x16(kf[kh][ds], qf[sub][ds], s[kh]);
            if (t == qt) {  // causal mask on diagonal tile
                #pragma unroll
                for (int kh = 0; kh < 2; ++kh)
                    #pragma unroll
                    for (int reg = 0; reg < 16; ++reg) {
                        const int kcol = (reg & 3) + 8 * (reg >> 2) + 4 * hi + kh * 32;
                        if (kcol > sub * 32 + l31) s[kh][reg] = -INFINITY;
                    }
            }
            // row max (own 32 + partner half)
            float pmax = s[0][0];
            #pragma unroll
            for (int kh = 0; kh < 2; ++kh)
                #pragma unroll
                for (int reg = 0; reg < 16; ++reg) pmax = fmaxf(pmax, s[kh][reg]);
            pmax = fmaxf(pmax, __shfl_xor(pmax, 32));
            const float mn = fmaxf(m_[sub], pmax);
            const float alpha = exp2f(m_[sub] - mn);
            m_[sub] = mn;
            l_[sub] *= alpha;
            o[sub][0] *= alpha;
            o[sub][1] *= alpha;
            // p = exp2(s-mn), accumulate l (in place)
            float lsum = 0.f;
            #pragma unroll
            for (int kh = 0; kh < 2; ++kh)
                #pragma unroll
                for (int reg = 0; reg < 16; ++reg) {
                    const float p = exp2f(s[kh][reg] - mn);
                    s[kh][reg] = p;
                    lsum += p;
                }
            l_[sub] += lsum;
            // pack P^T B-fragments: pa[ks] holds P[q=l31][ks*16+hi*8 ..+8]
            bf16x8 pa[4];
            #pragma unroll
            for (int kh = 0; kh < 2; ++kh)
                #pragma unroll
                for (int g = 0; g < 2; ++g) {
                    const int rb = g * 8;
                    const unsigned u01 = cvtpk_bf16(s[kh][rb + 0], s[kh][rb + 1]);
                    const unsigned u23 = cvtpk_bf16(s[kh][rb + 2], s[kh][rb + 3]);
                    const unsigned u45 = cvtpk_bf16(s[kh][rb + 4], s[kh][rb + 5]);
                    const unsigned u67 = cvtpk_bf16(s[kh][rb + 6], s[kh][rb + 7]);
                    const unsigned x01 = __shfl_xor(u01, 32);
                    const unsigned x23 = __shfl_xor(u23, 32);
                    const unsigned x45 = __shfl_xor(u45, 32);
                    const unsigned x67 = __shfl_xor(u67, 32);
                    u32x4 wv;
                    wv[0] = hi ? x45 : u01;
                    wv[1] = hi ? x67 : u23;
                    wv[2] = hi ? u45 : x01;
                    wv[3] = hi ? u67 : x23;
                    pa[kh * 2 + g] = __builtin_bit_cast(bf16x8, wv);
                }
            // O^T += V^T P^T : lane gets O[q=l31][d=crow(reg,hi)+32*dh]
            #pragma unroll
            for (int ks = 0; ks < 4; ++ks)
                #pragma unroll
                for (int dh = 0; dh < 2; ++dh)
                    o[sub][dh] = MFMA32x32x16(vf[ks][dh], pa[ks], o[sub][dh]);
        }
    }

    const int bb = bh / Hq, h = bh - bb * Hq;
    #pragma unroll
    for (int sub = 0; sub < 2; ++sub) {
        const float ltot = l_[sub] + __shfl_xor(l_[sub], 32);
        const float inv = 1.f / ltot;
        const int q = q0 + sub * 32 + l31;
        bf16* yp = Y + ((size_t)bb * Tq + q) * Cq + h * Dq;
        #pragma unroll
        for (int dh = 0; dh < 2; ++dh)
            #pragma unroll
            for (int rg = 0; rg < 4; ++rg) {
                const int d0 = 8 * rg + 4 * hi + 32 * dh;
                bf16x4 ov;
                #pragma unroll
                for (int j = 0; j < 4; ++j) ov[j] = (bf16)(o[sub][dh][rg * 4 + j] * inv);
                *reinterpret_cast<bf16x4*>(yp + d0) = ov;
            }
    }
}

// ---------------- Proj GEMM (bf16 MFMA, dbuf DMA): [8192x768]x[768x768] ------
__global__ __launch_bounds__(256) void gemm_proj(const bf16* __restrict__ A,
                                                 const bf16* __restrict__ Bt,
                                                 const float* __restrict__ bias,
                                                 float* __restrict__ out) {
    __shared__ bf16 As[2][128 * 64];
    __shared__ bf16 Bs[2][128 * 64];
    const int tid = threadIdx.x;
    const int w = tid >> 6, l = tid & 63;
    const int lane16 = l & 15, kg = l >> 4;
    const int wr = w >> 1, wc = w & 1;
    const int flat = blockIdx.y * gridDim.x + blockIdx.x;
    const int nid = (flat & 7) * 48 + (flat >> 3);
    const int bn0 = (nid % 6) * 128, bm0 = (nid / 6) * 128;

    auto stage = [&](int k0, int buf) {
        #pragma unroll
        for (int j = 0; j < 4; ++j) {
            const int q8 = w * 4 + j;
            const int r  = q8 * 8 + (l >> 3);
            const int c16 = (l & 7) ^ (r & 7);
            gload16(A + (size_t)(bm0 + r) * Cq + k0 + c16 * 8, &As[buf][q8 * 512]);
            gload16(Bt + (size_t)(bn0 + r) * Cq + k0 + c16 * 8, &Bs[buf][q8 * 512]);
        }
    };

    f32x4 acc[4][4] = {};
    stage(0, 0);
    __syncthreads();
    for (int kt = 0; kt < 12; ++kt) {
        if (kt < 11) stage((kt + 1) * 64, (kt + 1) & 1);
        bf16* Ac = As[kt & 1];
        bf16* Bc = Bs[kt & 1];
        #pragma unroll
        for (int ks = 0; ks < 2; ++ks) {
            bf16x8 af[4], bfr[4];
            #pragma unroll
            for (int m = 0; m < 4; ++m)
                af[m] = lds_v8(Ac, wr * 64 + m * 16 + lane16, ks * 64 + kg * 16);
            #pragma unroll
            for (int n = 0; n < 4; ++n)
                bfr[n] = lds_v8(Bc, wc * 64 + n * 16 + lane16, ks * 64 + kg * 16);
            #pragma unroll
            for (int m = 0; m < 4; ++m)
                #pragma unroll
                for (int n = 0; n < 4; ++n)
                    acc[m][n] = MFMA16x16x32(af[m], bfr[n], acc[m][n]);
        }
        __syncthreads();
    }
    const int mrow0 = bm0 + wr * 64;
    const int ncol0 = bn0 + wc * 64;
    #pragma unroll
    for (int mi = 0; mi < 4; ++mi) {
        #pragma unroll
        for (int r = 0; r < 4; ++r) {
            const int grow = mrow0 + mi * 16 + kg * 4 + r;
            #pragma unroll
            for (int ni = 0; ni < 4; ++ni) {
                const int gcol = ncol0 + ni * 16 + lane16;
                out[(size_t)grow * Cq + gcol] = acc[mi][ni][r] + bias[gcol];
            }
        }
    }
}

extern "C" void kernel_launch(void* const* d_in, const int* in_sizes, int n_in,
                              void* d_out, int out_size, void* d_ws, size_t ws_size,
                              hipStream_t stream) {
    const float* x      = (const float*)d_in[0];
    const float* w_attn = (const float*)d_in[1];
    const float* b_attn = (const float*)d_in[2];
    const float* w_proj = (const float*)d_in[3];
    const float* b_proj = (const float*)d_in[4];
    float* out = (float*)d_out;

    char* ws = (char*)d_ws;
    bf16* Ax  = (bf16*)ws; ws += (size_t)MROWS * Cq * 2;
    bf16* WaT = (bf16*)ws; ws += (size_t)N_QKV * Cq * 2;
    bf16* WpT = (bf16*)ws; ws += (size_t)Cq * Cq * 2;
    bf16* Qw  = (bf16*)ws; ws += (size_t)MROWS * Cq * 2;   // [B,H,T,D], x0.125*log2e
    bf16* Kw  = (bf16*)ws; ws += (size_t)MROWS * Cq * 2;   // [B,H,T,D]
    bf16* Vtw = (bf16*)ws; ws += (size_t)MROWS * Cq * 2;   // [B,H,D,T]
    bf16* Yw  = (bf16*)ws; ws += (size_t)MROWS * Cq * 2;   // attn out [M][C]

    f32_to_bf16<<<(MROWS * Cq / 8 + 255) / 256, 256, 0, stream>>>(x, Ax, MROWS * Cq / 8);
    transpose_f32_bf16<<<(Cq * N_QKV + 255) / 256, 256, 0, stream>>>(w_attn, WaT, Cq, N_QKV);
    transpose_f32_bf16<<<(Cq * Cq + 255) / 256, 256, 0, stream>>>(w_proj, WpT, Cq, Cq);
    gemm_qkv<<<dim3(18, 64), 256, 0, stream>>>(Ax, WaT, b_attn, Qw, Kw, Vtw);
    attn_mfma<<<dim3(384), 256, 0, stream>>>(Qw, Kw, Vtw, Yw);
    gemm_proj<<<dim3(6, 64), 256, 0, stream>>>(Yw, WpT, b_proj, out);
}